// Round 1
// baseline (772.406 us; speedup 1.0000x reference)
//
#include <hip/hip_runtime.h>

#define Bsz 16
#define Nn  100000
#define Ee  2000000
#define Dd  512
#define Cc  10
#define NB  (Nn * Bsz)

// ---- ordered-uint encoding for float atomic min/max ----
__device__ __forceinline__ unsigned enc_f(float f) {
    unsigned u = __float_as_uint(f);
    return (u & 0x80000000u) ? ~u : (u | 0x80000000u);
}
__device__ __forceinline__ float dec_f(unsigned e) {
    unsigned u = (e & 0x80000000u) ? (e ^ 0x80000000u) : ~e;
    return __uint_as_float(u);
}

// w[e] = edge_weight[e] * tanh(mult[e])  (once per call, reused 4 passes x 16 batches)
__global__ void prep_w(const float* __restrict__ ew, const float* __restrict__ mult,
                       float* __restrict__ w) {
    int i = blockIdx.x * blockDim.x + threadIdx.x;
    if (i < Ee) w[i] = ew[i] * tanhf(mult[i]);
}

// transpose x (B,N) -> xb[n*16+b]; thr[n] = |nt[n]|
__global__ void prep_x(const float* __restrict__ x, const float* __restrict__ nt,
                       float* __restrict__ xb, float* __restrict__ thr) {
    int i = blockIdx.x * blockDim.x + threadIdx.x;
    if (i < NB) {
        int n = i >> 4, b = i & 15;
        xb[i] = x[b * Nn + n];
        if (b == 0) thr[n] = fabsf(nt[n]);
    }
}

__global__ void init_mm(unsigned* mm) {
    if (threadIdx.x == 0) { mm[0] = 0xFFFFFFFFu; mm[1] = 0u; }
}

// thread per (edge, batch): 16 consecutive lanes share one edge
__global__ void scatter(const int* __restrict__ srcv, const int* __restrict__ dstv,
                        const float* __restrict__ w, const float* __restrict__ xb,
                        float* __restrict__ aggr) {
    int i = blockIdx.x * blockDim.x + threadIdx.x;   // < 32M, fits int
    if (i < Ee * 16) {
        int e = i >> 4, b = i & 15;
        float val = xb[srcv[e] * 16 + b] * w[e];
        atomicAdd(&aggr[dstv[e] * 16 + b], val);
    }
}

__global__ void reduce_mm(const float* __restrict__ aggr, unsigned* __restrict__ mm) {
    float lmin = INFINITY, lmax = -INFINITY;
    for (int i = blockIdx.x * blockDim.x + threadIdx.x; i < NB;
         i += gridDim.x * blockDim.x) {
        float v = aggr[i];
        lmin = fminf(lmin, v);
        lmax = fmaxf(lmax, v);
    }
    #pragma unroll
    for (int off = 32; off > 0; off >>= 1) {
        lmin = fminf(lmin, __shfl_down(lmin, off));
        lmax = fmaxf(lmax, __shfl_down(lmax, off));
    }
    __shared__ float smin[4], smax[4];
    int wid = threadIdx.x >> 6, lane = threadIdx.x & 63;
    if (lane == 0) { smin[wid] = lmin; smax[wid] = lmax; }
    __syncthreads();
    if (threadIdx.x == 0) {
        float m0 = smin[0], M0 = smax[0];
        #pragma unroll
        for (int k = 1; k < 4; k++) { m0 = fminf(m0, smin[k]); M0 = fmaxf(M0, smax[k]); }
        atomicMin(&mm[0], enc_f(m0));
        atomicMax(&mm[1], enc_f(M0));
    }
}

__global__ void update(const float* __restrict__ aggr, const float* __restrict__ thr,
                       const unsigned* __restrict__ mm, float* __restrict__ xb) {
    int i = blockIdx.x * blockDim.x + threadIdx.x;
    if (i < NB) {
        float amin = dec_f(mm[0]), amax = dec_f(mm[1]);
        float inv = 1.0f / (amax - amin);
        int n = i >> 4;
        float v = (aggr[i] - amin) * inv - thr[n];
        xb[i] = 1.0f / (1.0f + expf(-v));
    }
}

// gather decision nodes + (16x512)@(512x10) matmul, single block of 512 threads
__global__ void final_k(const float* __restrict__ xb, const int* __restrict__ dix,
                        const float* __restrict__ fcw, const float* __restrict__ fcb,
                        float* __restrict__ out) {
    __shared__ float xd[Dd][Bsz];   // 32 KB
    int j = threadIdx.x;
    int n = dix[j];
    #pragma unroll
    for (int b = 0; b < Bsz; b++) xd[j][b] = xb[n * 16 + b];
    __syncthreads();
    if (j < Bsz * Cc) {
        int b = j / Cc, c = j % Cc;
        float acc = fcb[c];
        for (int k = 0; k < Dd; k++) acc += xd[k][b] * fcw[c * Dd + k];
        out[b * Cc + c] = acc;
    }
}

extern "C" void kernel_launch(void* const* d_in, const int* in_sizes, int n_in,
                              void* d_out, int out_size, void* d_ws, size_t ws_size,
                              hipStream_t stream) {
    const float* x    = (const float*)d_in[0];
    const float* ew   = (const float*)d_in[1];
    const float* mult = (const float*)d_in[2];
    const float* nt   = (const float*)d_in[3];
    const float* fcw  = (const float*)d_in[4];
    const float* fcb  = (const float*)d_in[5];
    const int*   ei   = (const int*)d_in[6];
    const int*   dix  = (const int*)d_in[7];
    float* out = (float*)d_out;

    float* w    = (float*)d_ws;        // E
    float* xb   = w + Ee;              // NB
    float* aggr = xb + NB;             // NB
    float* thr  = aggr + NB;           // N
    unsigned* mm = (unsigned*)(thr + Nn);  // 2

    const int* srcv = ei;
    const int* dstv = ei + Ee;

    prep_w<<<(Ee + 255) / 256, 256, 0, stream>>>(ew, mult, w);
    prep_x<<<(NB + 255) / 256, 256, 0, stream>>>(x, nt, xb, thr);

    for (int p = 0; p < 4; p++) {
        hipMemsetAsync(aggr, 0, (size_t)NB * sizeof(float), stream);
        init_mm<<<1, 64, 0, stream>>>(mm);
        scatter<<<(Ee * 16 + 255) / 256, 256, 0, stream>>>(srcv, dstv, w, xb, aggr);
        reduce_mm<<<2048, 256, 0, stream>>>(aggr, mm);
        update<<<(NB + 255) / 256, 256, 0, stream>>>(aggr, thr, mm, xb);
    }

    final_k<<<1, 512, 0, stream>>>(xb, dix, fcw, fcb, out);
}